// Round 1
// baseline (1439.785 us; speedup 1.0000x reference)
//
#include <hip/hip_runtime.h>
#include <hip/hip_bf16.h>

#define NNODES 100000
#define NEDGES 1600000

typedef __attribute__((ext_vector_type(8))) short bf16x8;
typedef __attribute__((ext_vector_type(4))) short bf16x4;
typedef __attribute__((ext_vector_type(2))) short bf16x2;
typedef __attribute__((ext_vector_type(4))) float f32x4;
typedef __attribute__((ext_vector_type(2))) float f32x2;

static __device__ __forceinline__ short f2bf(float f) {
  __hip_bfloat16 b = __float2bfloat16(f);
  return __builtin_bit_cast(short, b);
}

// ---------------- weight transpose+convert: Wt[n][k] = bf16(W[k][n]) ----------------
__global__ void wtrans_kernel(const float* __restrict__ W, short* __restrict__ Wt,
                              int K, int Nvalid, int Npad) {
  int idx = blockIdx.x * blockDim.x + threadIdx.x;
  if (idx >= Npad * K) return;
  int n = idx / K, k = idx - n * K;
  Wt[idx] = (n < Nvalid) ? f2bf(W[(size_t)k * Nvalid + n]) : (short)0;
}

// ---------------- CSR build ----------------
__global__ void hist_kernel(const int* __restrict__ ei, int* __restrict__ deg) {
  int e = blockIdx.x * blockDim.x + threadIdx.x;
  if (e < NEDGES) atomicAdd(&deg[ei[NEDGES + e]], 1);
}

// block scans 1024 elements (256 thr x 4), writes local-exclusive into out, block sum to bsums
__global__ void scan1_kernel(const int* __restrict__ deg, int* __restrict__ out,
                             int* __restrict__ bsums) {
  __shared__ int lds[256];
  int tid = threadIdx.x;
  int base = blockIdx.x * 1024 + tid * 4;
  int v[4];
#pragma unroll
  for (int j = 0; j < 4; j++) v[j] = (base + j < NNODES) ? deg[base + j] : 0;
  int s = v[0] + v[1] + v[2] + v[3];
  lds[tid] = s;
  __syncthreads();
  for (int off = 1; off < 256; off <<= 1) {
    int t = (tid >= off) ? lds[tid - off] : 0;
    __syncthreads();
    lds[tid] += t;
    __syncthreads();
  }
  int incl = lds[tid];
  if (tid == 255) bsums[blockIdx.x] = incl;
  int run = incl - s;  // exclusive
#pragma unroll
  for (int j = 0; j < 4; j++) {
    if (base + j < NNODES) out[base + j] = run;
    run += v[j];
  }
}

__global__ void scan2_kernel(const int* __restrict__ bsums, int* __restrict__ bex, int nb) {
  __shared__ int lds[128];
  int tid = threadIdx.x;
  int s = (tid < nb) ? bsums[tid] : 0;
  lds[tid] = s;
  __syncthreads();
  for (int off = 1; off < 128; off <<= 1) {
    int t = (tid >= off) ? lds[tid - off] : 0;
    __syncthreads();
    lds[tid] += t;
    __syncthreads();
  }
  if (tid < nb) bex[tid] = lds[tid] - s;
}

__global__ void scan3_kernel(int* __restrict__ rowptr, int* __restrict__ cursor,
                             const int* __restrict__ bex) {
  int i = blockIdx.x * blockDim.x + threadIdx.x;
  if (i < NNODES) {
    int v = rowptr[i] + bex[i >> 10];
    rowptr[i] = v;
    cursor[i] = v;
  }
  if (i == 0) rowptr[NNODES] = NEDGES;
}

__global__ void scatter_kernel(const int* __restrict__ ei, const float* __restrict__ ew,
                               int* __restrict__ cursor, int* __restrict__ csrc,
                               float* __restrict__ cw) {
  int e = blockIdx.x * blockDim.x + threadIdx.x;
  if (e >= NEDGES) return;
  int s = ei[e], d = ei[NEDGES + e];
  int p = atomicAdd(&cursor[d], 1);
  csrc[p] = s;
  cw[p] = ew[e];
}

// ---------------- GEMM: C[M x nvalid] = A[M x K] * Wt^T, Wt is [NT*16 x K] bf16 ----------------
// one wave per 16-row block, covering all NT 16-col tiles; 4 waves per 256-thr block
template <int NT, bool AF32>
__global__ void gemm_kernel(const void* __restrict__ Aptr, const short* __restrict__ Wt,
                            const float* __restrict__ bias, float* __restrict__ C,
                            int K, int ldc, int nvalid) {
  int lane = threadIdx.x & 63;
  int wv = threadIdx.x >> 6;
  int rb = blockIdx.x * 4 + wv;
  if (rb * 16 >= NNODES) return;
  int quad = lane >> 4;
  int col = lane & 15;
  int m = rb * 16 + col;
  f32x4 acc[NT];
#pragma unroll
  for (int t = 0; t < NT; t++) acc[t] = (f32x4){0.f, 0.f, 0.f, 0.f};
  int ksteps = K >> 5;
  for (int ks = 0; ks < ksteps; ks++) {
    int k0 = (ks << 5) + (quad << 3);
    bf16x8 a;
    if (AF32) {
      const float* ap = (const float*)Aptr + (size_t)m * K + k0;
      f32x4 a0 = *(const f32x4*)ap;
      f32x4 a1 = *(const f32x4*)(ap + 4);
#pragma unroll
      for (int j = 0; j < 4; j++) { a[j] = f2bf(a0[j]); a[4 + j] = f2bf(a1[j]); }
    } else {
      a = *(const bf16x8*)((const short*)Aptr + (size_t)m * K + k0);
    }
#pragma unroll
    for (int t = 0; t < NT; t++) {
      int n = t * 16 + col;
      bf16x8 b = *(const bf16x8*)(Wt + (size_t)n * K + k0);
      acc[t] = __builtin_amdgcn_mfma_f32_16x16x32_bf16(a, b, acc[t], 0, 0, 0);
    }
  }
  int r0 = rb * 16 + quad * 4;
#pragma unroll
  for (int t = 0; t < NT; t++) {
    int n = t * 16 + col;
    if (n < nvalid) {
      float bv = bias ? bias[n] : 0.f;
#pragma unroll
      for (int r = 0; r < 4; r++)
        C[(size_t)(r0 + r) * ldc + n] = acc[t][r] + bv;
    }
  }
}

// ---------------- SpMM d=256: one wave per dst node, float4 per lane; +bias, relu, ->bf16 ----------------
__global__ void spmm1_kernel(const int* __restrict__ rowptr, const int* __restrict__ csrc,
                             const float* __restrict__ cw, const float* __restrict__ S,
                             const float* __restrict__ bias, short* __restrict__ H) {
  int node = blockIdx.x * 4 + (threadIdx.x >> 6);
  if (node >= NNODES) return;
  int lane = threadIdx.x & 63;
  int c0 = lane * 4;
  float a0 = 0.f, a1 = 0.f, a2 = 0.f, a3 = 0.f;
  int beg = rowptr[node], end = rowptr[node + 1];
  for (int i = beg; i < end; i++) {
    int s = csrc[i];
    float w = cw[i];
    f32x4 v = *(const f32x4*)(S + (size_t)s * 256 + c0);
    a0 += w * v[0]; a1 += w * v[1]; a2 += w * v[2]; a3 += w * v[3];
  }
  bf16x4 h;
  float r;
  r = a0 + bias[c0 + 0]; h[0] = f2bf(fmaxf(r, 0.f));
  r = a1 + bias[c0 + 1]; h[1] = f2bf(fmaxf(r, 0.f));
  r = a2 + bias[c0 + 2]; h[2] = f2bf(fmaxf(r, 0.f));
  r = a3 + bias[c0 + 3]; h[3] = f2bf(fmaxf(r, 0.f));
  *(bf16x4*)(H + (size_t)node * 256 + c0) = h;
}

// ---------------- SpMM d=128: one wave per dst node, float2 per lane; +bias, relu, ->bf16 ----------------
__global__ void spmm2_kernel(const int* __restrict__ rowptr, const int* __restrict__ csrc,
                             const float* __restrict__ cw, const float* __restrict__ S,
                             const float* __restrict__ bias, short* __restrict__ H) {
  int node = blockIdx.x * 4 + (threadIdx.x >> 6);
  if (node >= NNODES) return;
  int lane = threadIdx.x & 63;
  int c0 = lane * 2;
  float a0 = 0.f, a1 = 0.f;
  int beg = rowptr[node], end = rowptr[node + 1];
  for (int i = beg; i < end; i++) {
    int s = csrc[i];
    float w = cw[i];
    f32x2 v = *(const f32x2*)(S + (size_t)s * 128 + c0);
    a0 += w * v[0]; a1 += w * v[1];
  }
  bf16x2 h;
  float r;
  r = a0 + bias[c0 + 0]; h[0] = f2bf(fmaxf(r, 0.f));
  r = a1 + bias[c0 + 1]; h[1] = f2bf(fmaxf(r, 0.f));
  *(bf16x2*)(H + (size_t)node * 128 + c0) = h;
}

// ---------------- SpMM d=40 + bias + log_softmax ----------------
__global__ void spmm3_kernel(const int* __restrict__ rowptr, const int* __restrict__ csrc,
                             const float* __restrict__ cw, const float* __restrict__ S3,
                             const float* __restrict__ b3, float* __restrict__ out1) {
  int node = blockIdx.x * 4 + (threadIdx.x >> 6);
  if (node >= NNODES) return;
  int lane = threadIdx.x & 63;
  bool act = lane < 40;
  float acc = 0.f;
  int beg = rowptr[node], end = rowptr[node + 1];
  for (int i = beg; i < end; i++) {
    int s = csrc[i];
    float w = cw[i];
    if (act) acc += w * S3[(size_t)s * 40 + lane];
  }
  if (act) acc += b3[lane];
  float v = act ? acc : -__builtin_inff();
  for (int off = 32; off > 0; off >>= 1) v = fmaxf(v, __shfl_xor(v, off));
  float e = act ? expf(acc - v) : 0.f;
  for (int off = 32; off > 0; off >>= 1) e += __shfl_xor(e, off);
  float ls = logf(e);
  if (act) out1[(size_t)node * 40 + lane] = acc - v - ls;
}

extern "C" void kernel_launch(void* const* d_in, const int* in_sizes, int n_in,
                              void* d_out, int out_size, void* d_ws, size_t ws_size,
                              hipStream_t stream) {
  const float* x  = (const float*)d_in[0];
  const int*   ei = (const int*)d_in[1];
  const float* ew = (const float*)d_in[2];
  const float* W1 = (const float*)d_in[3];
  const float* b1 = (const float*)d_in[4];
  const float* W2 = (const float*)d_in[5];
  const float* b2 = (const float*)d_in[6];
  const float* W3 = (const float*)d_in[7];
  const float* b3 = (const float*)d_in[8];
  const float* We = (const float*)d_in[9];
  const float* be = (const float*)d_in[10];
  float* out1 = (float*)d_out;                         // 100000 x 40 (log_softmax)
  float* out2 = (float*)d_out + (size_t)NNODES * 40;   // 100000 x 128

  char* w = (char*)d_ws;
  size_t off = 0;
  auto alloc = [&](size_t bytes) -> char* {
    char* p = w + off;
    off += (bytes + 255) & ~(size_t)255;
    return p;
  };
  int*   deg    = (int*)alloc((size_t)NNODES * 4);
  int*   rowptr = (int*)alloc((size_t)(NNODES + 1) * 4);
  int*   cursor = (int*)alloc((size_t)NNODES * 4);
  int*   bsums  = (int*)alloc(512);
  int*   bex    = (int*)alloc(512);
  int*   csrc   = (int*)alloc((size_t)NEDGES * 4);
  float* cw     = (float*)alloc((size_t)NEDGES * 4);
  short* Wt1    = (short*)alloc((size_t)256 * 512 * 2);
  short* Wt2    = (short*)alloc((size_t)128 * 256 * 2);
  short* Wt3    = (short*)alloc((size_t)48 * 128 * 2);
  short* Wte    = (short*)alloc((size_t)128 * 256 * 2);
  float* Sbuf   = (float*)alloc((size_t)NNODES * 256 * 4);  // S1 / S2 / S3 aliased
  short* Hbf    = (short*)alloc((size_t)NNODES * 256 * 2);
  short* Tbf    = (short*)alloc((size_t)NNODES * 128 * 2);

  // --- CSR build ---
  hipMemsetAsync(deg, 0, (size_t)NNODES * 4, stream);
  hist_kernel<<<(NEDGES + 255) / 256, 256, 0, stream>>>(ei, deg);
  int nb = (NNODES + 1023) / 1024;
  scan1_kernel<<<nb, 256, 0, stream>>>(deg, rowptr, bsums);
  scan2_kernel<<<1, 128, 0, stream>>>(bsums, bex, nb);
  scan3_kernel<<<(NNODES + 255) / 256, 256, 0, stream>>>(rowptr, cursor, bex);
  scatter_kernel<<<(NEDGES + 255) / 256, 256, 0, stream>>>(ei, ew, cursor, csrc, cw);

  // --- weight transpose+bf16 ---
  wtrans_kernel<<<(256 * 512 + 255) / 256, 256, 0, stream>>>(W1, Wt1, 512, 256, 256);
  wtrans_kernel<<<(128 * 256 + 255) / 256, 256, 0, stream>>>(W2, Wt2, 256, 128, 128);
  wtrans_kernel<<<(48 * 128 + 255) / 256, 256, 0, stream>>>(W3, Wt3, 128, 40, 48);
  wtrans_kernel<<<(128 * 256 + 255) / 256, 256, 0, stream>>>(We, Wte, 256, 128, 128);

  int gblocks = (NNODES / 16 + 3) / 4;
  int sblocks = (NNODES + 3) / 4;

  // layer 1: S1 = x @ W1 ; h = relu(A*S1 + b1) -> bf16
  gemm_kernel<16, true><<<gblocks, 256, 0, stream>>>(x, Wt1, nullptr, Sbuf, 512, 256, 256);
  spmm1_kernel<<<sblocks, 256, 0, stream>>>(rowptr, csrc, cw, Sbuf, b1, Hbf);
  // layer 2: S2 = h @ W2 ; t = relu(A*S2 + b2) -> bf16
  gemm_kernel<8, false><<<gblocks, 256, 0, stream>>>(Hbf, Wt2, nullptr, Sbuf, 256, 128, 128);
  spmm2_kernel<<<sblocks, 256, 0, stream>>>(rowptr, csrc, cw, Sbuf, b2, Tbf);
  // out2 = h @ We + be
  gemm_kernel<8, false><<<gblocks, 256, 0, stream>>>(Hbf, Wte, be, out2, 256, 128, 128);
  // layer 3: S3 = t @ W3 ; out1 = log_softmax(A*S3 + b3)
  gemm_kernel<3, false><<<gblocks, 256, 0, stream>>>(Tbf, Wt3, nullptr, Sbuf, 128, 40, 40);
  spmm3_kernel<<<sblocks, 256, 0, stream>>>(rowptr, csrc, cw, Sbuf, b3, out1);
}

// Round 2
// 1089.123 us; speedup vs baseline: 1.3220x; 1.3220x over previous
//
#include <hip/hip_runtime.h>
#include <hip/hip_bf16.h>

#define NNODES 100000
#define NEDGES 1600000

typedef __attribute__((ext_vector_type(8))) short bf16x8;
typedef __attribute__((ext_vector_type(4))) short bf16x4;
typedef __attribute__((ext_vector_type(2))) short bf16x2;
typedef __attribute__((ext_vector_type(4))) float f32x4;
typedef __attribute__((ext_vector_type(2))) float f32x2;

static __device__ __forceinline__ short f2bf(float f) {
  __hip_bfloat16 b = __float2bfloat16(f);
  return __builtin_bit_cast(short, b);
}
static __device__ __forceinline__ float bf2f(short s) {
  unsigned int u = ((unsigned int)(unsigned short)s) << 16;
  return __builtin_bit_cast(float, u);
}

// ---------------- weight transpose+convert: Wt[n][k] = bf16(W[k][n]) ----------------
__global__ void wtrans_kernel(const float* __restrict__ W, short* __restrict__ Wt,
                              int K, int Nvalid, int Npad) {
  int idx = blockIdx.x * blockDim.x + threadIdx.x;
  if (idx >= Npad * K) return;
  int n = idx / K, k = idx - n * K;
  Wt[idx] = (n < Nvalid) ? f2bf(W[(size_t)k * Nvalid + n]) : (short)0;
}

// ---------------- CSR build ----------------
__global__ void hist_kernel(const int* __restrict__ ei, int* __restrict__ deg) {
  int e = blockIdx.x * blockDim.x + threadIdx.x;
  if (e < NEDGES) atomicAdd(&deg[ei[NEDGES + e]], 1);
}

__global__ void scan1_kernel(const int* __restrict__ deg, int* __restrict__ out,
                             int* __restrict__ bsums) {
  __shared__ int lds[256];
  int tid = threadIdx.x;
  int base = blockIdx.x * 1024 + tid * 4;
  int v[4];
#pragma unroll
  for (int j = 0; j < 4; j++) v[j] = (base + j < NNODES) ? deg[base + j] : 0;
  int s = v[0] + v[1] + v[2] + v[3];
  lds[tid] = s;
  __syncthreads();
  for (int off = 1; off < 256; off <<= 1) {
    int t = (tid >= off) ? lds[tid - off] : 0;
    __syncthreads();
    lds[tid] += t;
    __syncthreads();
  }
  int incl = lds[tid];
  if (tid == 255) bsums[blockIdx.x] = incl;
  int run = incl - s;
#pragma unroll
  for (int j = 0; j < 4; j++) {
    if (base + j < NNODES) out[base + j] = run;
    run += v[j];
  }
}

__global__ void scan2_kernel(const int* __restrict__ bsums, int* __restrict__ bex, int nb) {
  __shared__ int lds[128];
  int tid = threadIdx.x;
  int s = (tid < nb) ? bsums[tid] : 0;
  lds[tid] = s;
  __syncthreads();
  for (int off = 1; off < 128; off <<= 1) {
    int t = (tid >= off) ? lds[tid - off] : 0;
    __syncthreads();
    lds[tid] += t;
    __syncthreads();
  }
  if (tid < nb) bex[tid] = lds[tid] - s;
}

__global__ void scan3_kernel(int* __restrict__ rowptr, int* __restrict__ cursor,
                             const int* __restrict__ bex) {
  int i = blockIdx.x * blockDim.x + threadIdx.x;
  if (i < NNODES) {
    int v = rowptr[i] + bex[i >> 10];
    rowptr[i] = v;
    cursor[i] = v;
  }
  if (i == 0) rowptr[NNODES] = NEDGES;
}

__global__ void scatter_kernel(const int* __restrict__ ei, const float* __restrict__ ew,
                               int* __restrict__ cursor, int* __restrict__ csrc,
                               float* __restrict__ cw) {
  int e = blockIdx.x * blockDim.x + threadIdx.x;
  if (e >= NEDGES) return;
  int s = ei[e], d = ei[NEDGES + e];
  int p = atomicAdd(&cursor[d], 1);
  csrc[p] = s;
  cw[p] = ew[e];
}

// ---------------- tiled MFMA GEMM: 128x128 tile, BK=64, 4 waves of 64x64 ----------------
// A: [M x K] (f32 if AF32 else bf16), Wt: [N x K] bf16 (row n = output col n)
// EPI 0: bf16 store to Cp0 with leading dim ldc
// EPI 1: f32 store to Cp1 with leading dim nvalid, cols >= nvalid dropped
// EPI 2: split — col<128 -> bf16 Cp0 (ldc 128); col>=128 -> f32 Cp1 (ldc 128) + bias[col-128]
#define LDSTR 72  // 64 + 8 pad shorts: row stride 144 B -> 4-bank shift/row, <=2-way conflicts (free)
template <bool AF32, int EPI>
__launch_bounds__(256, 2)
__global__ void gemm_tiled(const void* __restrict__ Aptr, int K,
                           const short* __restrict__ Wt,
                           void* __restrict__ Cp0, float* __restrict__ Cp1,
                           const float* __restrict__ bias, int nvalid, int ldc) {
  __shared__ __align__(16) short As[128 * LDSTR];
  __shared__ __align__(16) short Bs[128 * LDSTR];
  int tid = threadIdx.x;
  int lane = tid & 63, wv = tid >> 6;
  int wr = wv >> 1, wc = wv & 1;
  int m0 = blockIdx.x * 128;
  int n0 = blockIdx.y * 128;
  f32x4 acc[4][4];
#pragma unroll
  for (int i = 0; i < 4; i++)
#pragma unroll
    for (int j = 0; j < 4; j++) acc[i][j] = (f32x4){0.f, 0.f, 0.f, 0.f};

  int srow = tid >> 3;        // 0..31
  int scol = (tid & 7) * 8;   // bf16 col offset, 16B chunks

  for (int k0 = 0; k0 < K; k0 += 64) {
#pragma unroll
    for (int p = 0; p < 4; p++) {
      int ml = p * 32 + srow;
      int arow = m0 + ml;
      if (arow >= NNODES) arow = NNODES - 1;  // clamp: dup rows, stores guarded
      bf16x8 av;
      if (AF32) {
        const float* ap = (const float*)Aptr + (size_t)arow * K + k0 + scol;
        f32x4 a0 = *(const f32x4*)ap;
        f32x4 a1 = *(const f32x4*)(ap + 4);
#pragma unroll
        for (int j = 0; j < 4; j++) { av[j] = f2bf(a0[j]); av[4 + j] = f2bf(a1[j]); }
      } else {
        av = *(const bf16x8*)((const short*)Aptr + (size_t)arow * K + k0 + scol);
      }
      *(bf16x8*)&As[ml * LDSTR + scol] = av;
      bf16x8 bv = *(const bf16x8*)(Wt + (size_t)(n0 + ml) * K + k0 + scol);
      *(bf16x8*)&Bs[ml * LDSTR + scol] = bv;
    }
    __syncthreads();
    int r = lane & 15, quad = lane >> 4;
#pragma unroll
    for (int kk = 0; kk < 64; kk += 32) {
      bf16x8 af[4], bfr[4];
#pragma unroll
      for (int i = 0; i < 4; i++)
        af[i] = *(const bf16x8*)&As[(wr * 64 + i * 16 + r) * LDSTR + kk + quad * 8];
#pragma unroll
      for (int j = 0; j < 4; j++)
        bfr[j] = *(const bf16x8*)&Bs[(wc * 64 + j * 16 + r) * LDSTR + kk + quad * 8];
#pragma unroll
      for (int i = 0; i < 4; i++)
#pragma unroll
        for (int j = 0; j < 4; j++)
          acc[i][j] = __builtin_amdgcn_mfma_f32_16x16x32_bf16(af[i], bfr[j], acc[i][j], 0, 0, 0);
    }
    __syncthreads();
  }

  int quad = lane >> 4, cl = lane & 15;
#pragma unroll
  for (int i = 0; i < 4; i++) {
    int rowb = m0 + wr * 64 + i * 16 + quad * 4;
#pragma unroll
    for (int rr = 0; rr < 4; rr++) {
      int row = rowb + rr;
      if (row < NNODES) {
#pragma unroll
        for (int j = 0; j < 4; j++) {
          int col = n0 + wc * 64 + j * 16 + cl;
          float v = acc[i][j][rr];
          if (EPI == 0) {
            ((short*)Cp0)[(size_t)row * ldc + col] = f2bf(v);
          } else if (EPI == 1) {
            if (col < nvalid) Cp1[(size_t)row * nvalid + col] = v;
          } else {
            if (col < 128) ((short*)Cp0)[(size_t)row * 128 + col] = f2bf(v);
            else Cp1[(size_t)row * 128 + (col - 128)] = v + bias[col - 128];
          }
        }
      }
    }
  }
}

// ---------------- SpMM d=256 bf16: one wave per dst node; +bias, relu, ->bf16 ----------------
__global__ void spmm1_kernel(const int* __restrict__ rowptr, const int* __restrict__ csrc,
                             const float* __restrict__ cw, const short* __restrict__ S,
                             const float* __restrict__ bias, short* __restrict__ H) {
  int node = blockIdx.x * 4 + (threadIdx.x >> 6);
  if (node >= NNODES) return;
  int lane = threadIdx.x & 63;
  int c0 = lane * 4;
  float a0 = 0.f, a1 = 0.f, a2 = 0.f, a3 = 0.f;
  int beg = rowptr[node], end = rowptr[node + 1];
  for (int i = beg; i < end; i++) {
    int s = csrc[i];
    float w = cw[i];
    bf16x4 v = *(const bf16x4*)(S + (size_t)s * 256 + c0);
    a0 += w * bf2f(v[0]); a1 += w * bf2f(v[1]); a2 += w * bf2f(v[2]); a3 += w * bf2f(v[3]);
  }
  bf16x4 h;
  float r;
  r = a0 + bias[c0 + 0]; h[0] = f2bf(fmaxf(r, 0.f));
  r = a1 + bias[c0 + 1]; h[1] = f2bf(fmaxf(r, 0.f));
  r = a2 + bias[c0 + 2]; h[2] = f2bf(fmaxf(r, 0.f));
  r = a3 + bias[c0 + 3]; h[3] = f2bf(fmaxf(r, 0.f));
  *(bf16x4*)(H + (size_t)node * 256 + c0) = h;
}

// ---------------- SpMM d=128 bf16 ----------------
__global__ void spmm2_kernel(const int* __restrict__ rowptr, const int* __restrict__ csrc,
                             const float* __restrict__ cw, const short* __restrict__ S,
                             const float* __restrict__ bias, short* __restrict__ H) {
  int node = blockIdx.x * 4 + (threadIdx.x >> 6);
  if (node >= NNODES) return;
  int lane = threadIdx.x & 63;
  int c0 = lane * 2;
  float a0 = 0.f, a1 = 0.f;
  int beg = rowptr[node], end = rowptr[node + 1];
  for (int i = beg; i < end; i++) {
    int s = csrc[i];
    float w = cw[i];
    bf16x2 v = *(const bf16x2*)(S + (size_t)s * 128 + c0);
    a0 += w * bf2f(v[0]); a1 += w * bf2f(v[1]);
  }
  bf16x2 h;
  float r;
  r = a0 + bias[c0 + 0]; h[0] = f2bf(fmaxf(r, 0.f));
  r = a1 + bias[c0 + 1]; h[1] = f2bf(fmaxf(r, 0.f));
  *(bf16x2*)(H + (size_t)node * 128 + c0) = h;
}

// ---------------- SpMM d=40 f32 + bias + log_softmax ----------------
__global__ void spmm3_kernel(const int* __restrict__ rowptr, const int* __restrict__ csrc,
                             const float* __restrict__ cw, const float* __restrict__ S3,
                             const float* __restrict__ b3, float* __restrict__ out1) {
  int node = blockIdx.x * 4 + (threadIdx.x >> 6);
  if (node >= NNODES) return;
  int lane = threadIdx.x & 63;
  bool act = lane < 40;
  float acc = 0.f;
  int beg = rowptr[node], end = rowptr[node + 1];
  for (int i = beg; i < end; i++) {
    int s = csrc[i];
    float w = cw[i];
    if (act) acc += w * S3[(size_t)s * 40 + lane];
  }
  if (act) acc += b3[lane];
  float v = act ? acc : -__builtin_inff();
  for (int off = 32; off > 0; off >>= 1) v = fmaxf(v, __shfl_xor(v, off));
  float e = act ? expf(acc - v) : 0.f;
  for (int off = 32; off > 0; off >>= 1) e += __shfl_xor(e, off);
  float ls = logf(e);
  if (act) out1[(size_t)node * 40 + lane] = acc - v - ls;
}

extern "C" void kernel_launch(void* const* d_in, const int* in_sizes, int n_in,
                              void* d_out, int out_size, void* d_ws, size_t ws_size,
                              hipStream_t stream) {
  const float* x  = (const float*)d_in[0];
  const int*   ei = (const int*)d_in[1];
  const float* ew = (const float*)d_in[2];
  const float* W1 = (const float*)d_in[3];
  const float* b1 = (const float*)d_in[4];
  const float* W2 = (const float*)d_in[5];
  const float* b2 = (const float*)d_in[6];
  const float* W3 = (const float*)d_in[7];
  const float* b3 = (const float*)d_in[8];
  const float* We = (const float*)d_in[9];
  const float* be = (const float*)d_in[10];
  float* out1 = (float*)d_out;                         // 100000 x 40 (log_softmax)
  float* out2 = (float*)d_out + (size_t)NNODES * 40;   // 100000 x 128

  char* w = (char*)d_ws;
  size_t off = 0;
  auto alloc = [&](size_t bytes) -> char* {
    char* p = w + off;
    off += (bytes + 255) & ~(size_t)255;
    return p;
  };
  int*   deg    = (int*)alloc((size_t)NNODES * 4);
  int*   rowptr = (int*)alloc((size_t)(NNODES + 1) * 4);
  int*   cursor = (int*)alloc((size_t)NNODES * 4);
  int*   bsums  = (int*)alloc(512);
  int*   bex    = (int*)alloc(512);
  int*   csrc   = (int*)alloc((size_t)NEDGES * 4);
  float* cw     = (float*)alloc((size_t)NEDGES * 4);
  short* Wt1    = (short*)alloc((size_t)256 * 512 * 2);
  short* Wt2e   = (short*)alloc((size_t)256 * 256 * 2);   // rows 0-127: W2t, 128-255: Wet
  short* Wt3    = (short*)alloc((size_t)128 * 128 * 2);   // rows 40-127 zero
  short* S1bf   = (short*)alloc((size_t)NNODES * 256 * 2);
  short* Hbf    = (short*)alloc((size_t)NNODES * 256 * 2);
  short* S2bf   = (short*)alloc((size_t)NNODES * 128 * 2);
  short* Tbf    = (short*)alloc((size_t)NNODES * 128 * 2);
  float* S3     = (float*)alloc((size_t)NNODES * 40 * 4);

  // --- CSR build ---
  hipMemsetAsync(deg, 0, (size_t)NNODES * 4, stream);
  hist_kernel<<<(NEDGES + 255) / 256, 256, 0, stream>>>(ei, deg);
  int nb = (NNODES + 1023) / 1024;
  scan1_kernel<<<nb, 256, 0, stream>>>(deg, rowptr, bsums);
  scan2_kernel<<<1, 128, 0, stream>>>(bsums, bex, nb);
  scan3_kernel<<<(NNODES + 255) / 256, 256, 0, stream>>>(rowptr, cursor, bex);
  scatter_kernel<<<(NEDGES + 255) / 256, 256, 0, stream>>>(ei, ew, cursor, csrc, cw);

  // --- weight transpose+bf16 ---
  wtrans_kernel<<<(256 * 512 + 255) / 256, 256, 0, stream>>>(W1, Wt1, 512, 256, 256);
  wtrans_kernel<<<(128 * 256 + 255) / 256, 256, 0, stream>>>(W2, Wt2e, 256, 128, 128);
  wtrans_kernel<<<(128 * 256 + 255) / 256, 256, 0, stream>>>(We, Wt2e + (size_t)128 * 256, 256, 128, 128);
  wtrans_kernel<<<(128 * 128 + 255) / 256, 256, 0, stream>>>(W3, Wt3, 128, 40, 128);

  int gblocks = (NNODES + 127) / 128;  // 782
  int sblocks = (NNODES + 3) / 4;

  // layer 1: S1 = bf16(x @ W1); h = bf16(relu(A*S1 + b1))
  gemm_tiled<true, 0><<<dim3(gblocks, 2), 256, 0, stream>>>(x, 512, Wt1, S1bf, nullptr, nullptr, 256, 256);
  spmm1_kernel<<<sblocks, 256, 0, stream>>>(rowptr, csrc, cw, S1bf, b1, Hbf);
  // fused layer2 + struct head: [S2 | out2] = h @ [W2 | We]; out2 += be
  gemm_tiled<false, 2><<<dim3(gblocks, 2), 256, 0, stream>>>(Hbf, 256, Wt2e, S2bf, out2, be, 256, 128);
  spmm2_kernel<<<sblocks, 256, 0, stream>>>(rowptr, csrc, cw, S2bf, b2, Tbf);
  // layer 3: S3 = t @ W3 (f32, 40 cols); out1 = log_softmax(A*S3 + b3)
  gemm_tiled<false, 1><<<dim3(gblocks, 1), 256, 0, stream>>>(Tbf, 128, Wt3, nullptr, S3, nullptr, 40, 40);
  spmm3_kernel<<<sblocks, 256, 0, stream>>>(rowptr, csrc, cw, S3, b3, out1);
}

// Round 3
// 884.476 us; speedup vs baseline: 1.6278x; 1.2314x over previous
//
#include <hip/hip_runtime.h>
#include <hip/hip_bf16.h>

#define NNODES 100000
#define NEDGES 1600000

typedef __attribute__((ext_vector_type(8))) short bf16x8;
typedef __attribute__((ext_vector_type(4))) short bf16x4;
typedef __attribute__((ext_vector_type(2))) short bf16x2;
typedef __attribute__((ext_vector_type(4))) float f32x4;
typedef __attribute__((ext_vector_type(2))) float f32x2;

static __device__ __forceinline__ short f2bf(float f) {
  __hip_bfloat16 b = __float2bfloat16(f);
  return __builtin_bit_cast(short, b);
}
static __device__ __forceinline__ float bf2f(short s) {
  unsigned int u = ((unsigned int)(unsigned short)s) << 16;
  return __builtin_bit_cast(float, u);
}
static __device__ __forceinline__ void fma4(f32x4& a, float w, bf16x4 v) {
  a[0] = fmaf(w, bf2f(v[0]), a[0]);
  a[1] = fmaf(w, bf2f(v[1]), a[1]);
  a[2] = fmaf(w, bf2f(v[2]), a[2]);
  a[3] = fmaf(w, bf2f(v[3]), a[3]);
}
static __device__ __forceinline__ void fma2(f32x2& a, float w, bf16x2 v) {
  a[0] = fmaf(w, bf2f(v[0]), a[0]);
  a[1] = fmaf(w, bf2f(v[1]), a[1]);
}

// ---------------- weight transpose+convert: Wt[n][k] = bf16(W[k][n]) ----------------
__global__ void wtrans_kernel(const float* __restrict__ W, short* __restrict__ Wt,
                              int K, int Nvalid, int Npad) {
  int idx = blockIdx.x * blockDim.x + threadIdx.x;
  if (idx >= Npad * K) return;
  int n = idx / K, k = idx - n * K;
  Wt[idx] = (n < Nvalid) ? f2bf(W[(size_t)k * Nvalid + n]) : (short)0;
}

// ---------------- CSR build ----------------
__global__ void hist_kernel(const int* __restrict__ ei, int* __restrict__ deg) {
  int e = blockIdx.x * blockDim.x + threadIdx.x;
  if (e < NEDGES) atomicAdd(&deg[ei[NEDGES + e]], 1);
}

__global__ void scan1_kernel(const int* __restrict__ deg, int* __restrict__ out,
                             int* __restrict__ bsums) {
  __shared__ int lds[256];
  int tid = threadIdx.x;
  int base = blockIdx.x * 1024 + tid * 4;
  int v[4];
#pragma unroll
  for (int j = 0; j < 4; j++) v[j] = (base + j < NNODES) ? deg[base + j] : 0;
  int s = v[0] + v[1] + v[2] + v[3];
  lds[tid] = s;
  __syncthreads();
  for (int off = 1; off < 256; off <<= 1) {
    int t = (tid >= off) ? lds[tid - off] : 0;
    __syncthreads();
    lds[tid] += t;
    __syncthreads();
  }
  int incl = lds[tid];
  if (tid == 255) bsums[blockIdx.x] = incl;
  int run = incl - s;
#pragma unroll
  for (int j = 0; j < 4; j++) {
    if (base + j < NNODES) out[base + j] = run;
    run += v[j];
  }
}

__global__ void scan2_kernel(const int* __restrict__ bsums, int* __restrict__ bex, int nb) {
  __shared__ int lds[128];
  int tid = threadIdx.x;
  int s = (tid < nb) ? bsums[tid] : 0;
  lds[tid] = s;
  __syncthreads();
  for (int off = 1; off < 128; off <<= 1) {
    int t = (tid >= off) ? lds[tid - off] : 0;
    __syncthreads();
    lds[tid] += t;
    __syncthreads();
  }
  if (tid < nb) bex[tid] = lds[tid] - s;
}

__global__ void scan3_kernel(int* __restrict__ rowptr, int* __restrict__ cursor,
                             const int* __restrict__ bex) {
  int i = blockIdx.x * blockDim.x + threadIdx.x;
  if (i < NNODES) {
    int v = rowptr[i] + bex[i >> 10];
    rowptr[i] = v;
    cursor[i] = v;
  }
  if (i == 0) rowptr[NNODES] = NEDGES;
}

// pack (src, weight) into one 8B record: one random store per edge, one scalar load later
__global__ void scatter_kernel(const int* __restrict__ ei, const float* __restrict__ ew,
                               int* __restrict__ cursor, int2* __restrict__ edat) {
  int e = blockIdx.x * blockDim.x + threadIdx.x;
  if (e >= NEDGES) return;
  int s = ei[e], d = ei[NEDGES + e];
  int p = atomicAdd(&cursor[d], 1);
  edat[p] = make_int2(s, __float_as_int(ew[e]));
}

// ---------------- tiled MFMA GEMM: 128x128 tile, BK=64, 4 waves of 64x64 ----------------
#define LDSTR 72
template <bool AF32, int EPI>
__launch_bounds__(256, 2)
__global__ void gemm_tiled(const void* __restrict__ Aptr, int K,
                           const short* __restrict__ Wt,
                           void* __restrict__ Cp0, float* __restrict__ Cp1,
                           const float* __restrict__ bias, int nvalid, int ldc) {
  __shared__ __align__(16) short As[128 * LDSTR];
  __shared__ __align__(16) short Bs[128 * LDSTR];
  int tid = threadIdx.x;
  int lane = tid & 63, wv = tid >> 6;
  int wr = wv >> 1, wc = wv & 1;
  int m0 = blockIdx.x * 128;
  int n0 = blockIdx.y * 128;
  f32x4 acc[4][4];
#pragma unroll
  for (int i = 0; i < 4; i++)
#pragma unroll
    for (int j = 0; j < 4; j++) acc[i][j] = (f32x4){0.f, 0.f, 0.f, 0.f};

  int srow = tid >> 3;
  int scol = (tid & 7) * 8;

  for (int k0 = 0; k0 < K; k0 += 64) {
#pragma unroll
    for (int p = 0; p < 4; p++) {
      int ml = p * 32 + srow;
      int arow = m0 + ml;
      if (arow >= NNODES) arow = NNODES - 1;
      bf16x8 av;
      if (AF32) {
        const float* ap = (const float*)Aptr + (size_t)arow * K + k0 + scol;
        f32x4 a0 = *(const f32x4*)ap;
        f32x4 a1 = *(const f32x4*)(ap + 4);
#pragma unroll
        for (int j = 0; j < 4; j++) { av[j] = f2bf(a0[j]); av[4 + j] = f2bf(a1[j]); }
      } else {
        av = *(const bf16x8*)((const short*)Aptr + (size_t)arow * K + k0 + scol);
      }
      *(bf16x8*)&As[ml * LDSTR + scol] = av;
      bf16x8 bv = *(const bf16x8*)(Wt + (size_t)(n0 + ml) * K + k0 + scol);
      *(bf16x8*)&Bs[ml * LDSTR + scol] = bv;
    }
    __syncthreads();
    int r = lane & 15, quad = lane >> 4;
#pragma unroll
    for (int kk = 0; kk < 64; kk += 32) {
      bf16x8 af[4], bfr[4];
#pragma unroll
      for (int i = 0; i < 4; i++)
        af[i] = *(const bf16x8*)&As[(wr * 64 + i * 16 + r) * LDSTR + kk + quad * 8];
#pragma unroll
      for (int j = 0; j < 4; j++)
        bfr[j] = *(const bf16x8*)&Bs[(wc * 64 + j * 16 + r) * LDSTR + kk + quad * 8];
#pragma unroll
      for (int i = 0; i < 4; i++)
#pragma unroll
        for (int j = 0; j < 4; j++)
          acc[i][j] = __builtin_amdgcn_mfma_f32_16x16x32_bf16(af[i], bfr[j], acc[i][j], 0, 0, 0);
    }
    __syncthreads();
  }

  int quad = lane >> 4, cl = lane & 15;
#pragma unroll
  for (int i = 0; i < 4; i++) {
    int rowb = m0 + wr * 64 + i * 16 + quad * 4;
#pragma unroll
    for (int rr = 0; rr < 4; rr++) {
      int row = rowb + rr;
      if (row < NNODES) {
#pragma unroll
        for (int j = 0; j < 4; j++) {
          int col = n0 + wc * 64 + j * 16 + cl;
          float v = acc[i][j][rr];
          if (EPI == 0) {
            ((short*)Cp0)[(size_t)row * ldc + col] = f2bf(v);
          } else if (EPI == 1) {
            if (col < nvalid) Cp1[(size_t)row * nvalid + col] = v;
          } else {
            if (col < 128) ((short*)Cp0)[(size_t)row * 128 + col] = f2bf(v);
            else Cp1[(size_t)row * 128 + (col - 128)] = v + bias[col - 128];
          }
        }
      }
    }
  }
}

// ---------------- SpMM d=256 bf16, 8 gathers in flight ----------------
__global__ void spmm1_kernel(const int* __restrict__ rowptr, const int2* __restrict__ edat,
                             const short* __restrict__ S,
                             const float* __restrict__ bias, short* __restrict__ H) {
  int node = blockIdx.x * 4 + (threadIdx.x >> 6);
  if (node >= NNODES) return;
  int lane = threadIdx.x & 63;
  int c0 = lane * 4;
  const short* Sc = S + c0;
  f32x4 acc0 = (f32x4){0.f, 0.f, 0.f, 0.f};
  f32x4 acc1 = (f32x4){0.f, 0.f, 0.f, 0.f};
  int beg = rowptr[node], end = rowptr[node + 1];
  int i = beg;
  for (; i + 8 <= end; i += 8) {
    int2 e[8];
    bf16x4 v[8];
#pragma unroll
    for (int j = 0; j < 8; j++) e[j] = edat[i + j];
#pragma unroll
    for (int j = 0; j < 8; j++) v[j] = *(const bf16x4*)(Sc + (size_t)e[j].x * 256);
#pragma unroll
    for (int j = 0; j < 8; j++) {
      float w = __int_as_float(e[j].y);
      if (j & 1) fma4(acc1, w, v[j]); else fma4(acc0, w, v[j]);
    }
  }
  for (; i < end; i++) {
    int2 e = edat[i];
    fma4(acc0, __int_as_float(e.y), *(const bf16x4*)(Sc + (size_t)e.x * 256));
  }
  f32x4 a;
  a[0] = acc0[0] + acc1[0]; a[1] = acc0[1] + acc1[1];
  a[2] = acc0[2] + acc1[2]; a[3] = acc0[3] + acc1[3];
  f32x4 b = *(const f32x4*)(bias + c0);
  bf16x4 h;
#pragma unroll
  for (int j = 0; j < 4; j++) h[j] = f2bf(fmaxf(a[j] + b[j], 0.f));
  *(bf16x4*)(H + (size_t)node * 256 + c0) = h;
}

// ---------------- SpMM d=128 bf16, 8 gathers in flight ----------------
__global__ void spmm2_kernel(const int* __restrict__ rowptr, const int2* __restrict__ edat,
                             const short* __restrict__ S,
                             const float* __restrict__ bias, short* __restrict__ H) {
  int node = blockIdx.x * 4 + (threadIdx.x >> 6);
  if (node >= NNODES) return;
  int lane = threadIdx.x & 63;
  int c0 = lane * 2;
  const short* Sc = S + c0;
  f32x2 acc0 = (f32x2){0.f, 0.f};
  f32x2 acc1 = (f32x2){0.f, 0.f};
  int beg = rowptr[node], end = rowptr[node + 1];
  int i = beg;
  for (; i + 8 <= end; i += 8) {
    int2 e[8];
    bf16x2 v[8];
#pragma unroll
    for (int j = 0; j < 8; j++) e[j] = edat[i + j];
#pragma unroll
    for (int j = 0; j < 8; j++) v[j] = *(const bf16x2*)(Sc + (size_t)e[j].x * 128);
#pragma unroll
    for (int j = 0; j < 8; j++) {
      float w = __int_as_float(e[j].y);
      if (j & 1) fma2(acc1, w, v[j]); else fma2(acc0, w, v[j]);
    }
  }
  for (; i < end; i++) {
    int2 e = edat[i];
    fma2(acc0, __int_as_float(e.y), *(const bf16x2*)(Sc + (size_t)e.x * 128));
  }
  float a0 = acc0[0] + acc1[0], a1 = acc0[1] + acc1[1];
  bf16x2 h;
  h[0] = f2bf(fmaxf(a0 + bias[c0 + 0], 0.f));
  h[1] = f2bf(fmaxf(a1 + bias[c0 + 1], 0.f));
  *(bf16x2*)(H + (size_t)node * 128 + c0) = h;
}

// ---------------- SpMM d=40 f32 + bias + log_softmax, 8 gathers in flight ----------------
__global__ void spmm3_kernel(const int* __restrict__ rowptr, const int2* __restrict__ edat,
                             const float* __restrict__ S3,
                             const float* __restrict__ b3, float* __restrict__ out1) {
  int node = blockIdx.x * 4 + (threadIdx.x >> 6);
  if (node >= NNODES) return;
  int lane = threadIdx.x & 63;
  bool act = lane < 40;
  float acc0 = 0.f, acc1 = 0.f;
  int beg = rowptr[node], end = rowptr[node + 1];
  if (act) {
    int i = beg;
    for (; i + 8 <= end; i += 8) {
      int2 e[8];
      float v[8];
#pragma unroll
      for (int j = 0; j < 8; j++) e[j] = edat[i + j];
#pragma unroll
      for (int j = 0; j < 8; j++) v[j] = S3[(size_t)e[j].x * 40 + lane];
#pragma unroll
      for (int j = 0; j < 8; j++) {
        float w = __int_as_float(e[j].y);
        if (j & 1) acc1 = fmaf(w, v[j], acc1); else acc0 = fmaf(w, v[j], acc0);
      }
    }
    for (; i < end; i++) {
      int2 e = edat[i];
      acc0 = fmaf(__int_as_float(e.y), S3[(size_t)e.x * 40 + lane], acc0);
    }
  }
  float acc = acc0 + acc1;
  if (act) acc += b3[lane];
  float v = act ? acc : -__builtin_inff();
  for (int off = 32; off > 0; off >>= 1) v = fmaxf(v, __shfl_xor(v, off));
  float e = act ? expf(acc - v) : 0.f;
  for (int off = 32; off > 0; off >>= 1) e += __shfl_xor(e, off);
  float ls = logf(e);
  if (act) out1[(size_t)node * 40 + lane] = acc - v - ls;
}

extern "C" void kernel_launch(void* const* d_in, const int* in_sizes, int n_in,
                              void* d_out, int out_size, void* d_ws, size_t ws_size,
                              hipStream_t stream) {
  const float* x  = (const float*)d_in[0];
  const int*   ei = (const int*)d_in[1];
  const float* ew = (const float*)d_in[2];
  const float* W1 = (const float*)d_in[3];
  const float* b1 = (const float*)d_in[4];
  const float* W2 = (const float*)d_in[5];
  const float* b2 = (const float*)d_in[6];
  const float* W3 = (const float*)d_in[7];
  const float* b3 = (const float*)d_in[8];
  const float* We = (const float*)d_in[9];
  const float* be = (const float*)d_in[10];
  float* out1 = (float*)d_out;
  float* out2 = (float*)d_out + (size_t)NNODES * 40;

  char* w = (char*)d_ws;
  size_t off = 0;
  auto alloc = [&](size_t bytes) -> char* {
    char* p = w + off;
    off += (bytes + 255) & ~(size_t)255;
    return p;
  };
  int*   deg    = (int*)alloc((size_t)NNODES * 4);
  int*   rowptr = (int*)alloc((size_t)(NNODES + 1) * 4);
  int*   cursor = (int*)alloc((size_t)NNODES * 4);
  int*   bsums  = (int*)alloc(512);
  int*   bex    = (int*)alloc(512);
  int2*  edat   = (int2*)alloc((size_t)NEDGES * 8);
  short* Wt1    = (short*)alloc((size_t)256 * 512 * 2);
  short* Wt2e   = (short*)alloc((size_t)256 * 256 * 2);
  short* Wt3    = (short*)alloc((size_t)128 * 128 * 2);
  short* S1bf   = (short*)alloc((size_t)NNODES * 256 * 2);
  short* Hbf    = (short*)alloc((size_t)NNODES * 256 * 2);
  short* S2bf   = (short*)alloc((size_t)NNODES * 128 * 2);
  short* Tbf    = (short*)alloc((size_t)NNODES * 128 * 2);
  float* S3     = (float*)alloc((size_t)NNODES * 40 * 4);

  hipMemsetAsync(deg, 0, (size_t)NNODES * 4, stream);
  hist_kernel<<<(NEDGES + 255) / 256, 256, 0, stream>>>(ei, deg);
  int nb = (NNODES + 1023) / 1024;
  scan1_kernel<<<nb, 256, 0, stream>>>(deg, rowptr, bsums);
  scan2_kernel<<<1, 128, 0, stream>>>(bsums, bex, nb);
  scan3_kernel<<<(NNODES + 255) / 256, 256, 0, stream>>>(rowptr, cursor, bex);
  scatter_kernel<<<(NEDGES + 255) / 256, 256, 0, stream>>>(ei, ew, cursor, edat);

  wtrans_kernel<<<(256 * 512 + 255) / 256, 256, 0, stream>>>(W1, Wt1, 512, 256, 256);
  wtrans_kernel<<<(128 * 256 + 255) / 256, 256, 0, stream>>>(W2, Wt2e, 256, 128, 128);
  wtrans_kernel<<<(128 * 256 + 255) / 256, 256, 0, stream>>>(We, Wt2e + (size_t)128 * 256, 256, 128, 128);
  wtrans_kernel<<<(128 * 128 + 255) / 256, 256, 0, stream>>>(W3, Wt3, 128, 40, 128);

  int gblocks = (NNODES + 127) / 128;
  int sblocks = (NNODES + 3) / 4;

  gemm_tiled<true, 0><<<dim3(gblocks, 2), 256, 0, stream>>>(x, 512, Wt1, S1bf, nullptr, nullptr, 256, 256);
  spmm1_kernel<<<sblocks, 256, 0, stream>>>(rowptr, edat, S1bf, b1, Hbf);
  gemm_tiled<false, 2><<<dim3(gblocks, 2), 256, 0, stream>>>(Hbf, 256, Wt2e, S2bf, out2, be, 256, 128);
  spmm2_kernel<<<sblocks, 256, 0, stream>>>(rowptr, edat, S2bf, b2, Tbf);
  gemm_tiled<false, 1><<<dim3(gblocks, 1), 256, 0, stream>>>(Tbf, 128, Wt3, nullptr, S3, nullptr, 40, 40);
  spmm3_kernel<<<sblocks, 256, 0, stream>>>(rowptr, edat, S3, b3, out1);
}

// Round 4
// 788.973 us; speedup vs baseline: 1.8249x; 1.1210x over previous
//
#include <hip/hip_runtime.h>
#include <hip/hip_bf16.h>

#define NNODES 100000
#define NEDGES 1600000
#define BSH 7
#define NBUCK ((NNODES + 127) >> 7)   // 782 buckets of 128 nodes

typedef __attribute__((ext_vector_type(8))) short bf16x8;
typedef __attribute__((ext_vector_type(4))) short bf16x4;
typedef __attribute__((ext_vector_type(2))) short bf16x2;
typedef __attribute__((ext_vector_type(4))) float f32x4;
typedef __attribute__((ext_vector_type(2))) float f32x2;

static __device__ __forceinline__ short f2bf(float f) {
  __hip_bfloat16 b = __float2bfloat16(f);
  return __builtin_bit_cast(short, b);
}
static __device__ __forceinline__ float bf2f(short s) {
  unsigned int u = ((unsigned int)(unsigned short)s) << 16;
  return __builtin_bit_cast(float, u);
}
static __device__ __forceinline__ void fma4(f32x4& a, float w, bf16x4 v) {
  a[0] = fmaf(w, bf2f(v[0]), a[0]);
  a[1] = fmaf(w, bf2f(v[1]), a[1]);
  a[2] = fmaf(w, bf2f(v[2]), a[2]);
  a[3] = fmaf(w, bf2f(v[3]), a[3]);
}
static __device__ __forceinline__ void fma2(f32x2& a, float w, bf16x2 v) {
  a[0] = fmaf(w, bf2f(v[0]), a[0]);
  a[1] = fmaf(w, bf2f(v[1]), a[1]);
}

// ---------------- weight transpose+convert: Wt[n][k] = bf16(W[k][n]) ----------------
__global__ void wtrans_kernel(const float* __restrict__ W, short* __restrict__ Wt,
                              int K, int Nvalid, int Npad) {
  int idx = blockIdx.x * blockDim.x + threadIdx.x;
  if (idx >= Npad * K) return;
  int n = idx / K, k = idx - n * K;
  Wt[idx] = (n < Nvalid) ? f2bf(W[(size_t)k * Nvalid + n]) : (short)0;
}

// ---------------- CSR build: two-level counting sort ----------------
// P2: bucket histogram (LDS-aggregated)
__global__ void bcount_kernel(const int* __restrict__ ei, int* __restrict__ bcnt) {
  __shared__ int h[NBUCK];
  for (int i = threadIdx.x; i < NBUCK; i += 256) h[i] = 0;
  __syncthreads();
  int stride = gridDim.x * 256;
  for (int e = blockIdx.x * 256 + threadIdx.x; e < NEDGES; e += stride)
    atomicAdd(&h[ei[NEDGES + e] >> BSH], 1);
  __syncthreads();
  for (int i = threadIdx.x; i < NBUCK; i += 256)
    if (h[i]) atomicAdd(&bcnt[i], h[i]);
}

// P3: scan bucket counts -> bbase (exclusive, +sentinel), init bcur
__global__ void bscan_kernel(const int* __restrict__ bcnt, int* __restrict__ bbase,
                             int* __restrict__ bcur, int* __restrict__ rowptr) {
  __shared__ int lds[1024];
  int t = threadIdx.x;
  int c = (t < NBUCK) ? bcnt[t] : 0;
  lds[t] = c;
  __syncthreads();
  for (int off = 1; off < 1024; off <<= 1) {
    int v = (t >= off) ? lds[t - off] : 0;
    __syncthreads();
    lds[t] += v;
    __syncthreads();
  }
  if (t < NBUCK) {
    int ex = lds[t] - c;
    bbase[t] = ex;
    bcur[t] = ex;
  }
  if (t == NBUCK) bbase[t] = NEDGES;
  if (t == 0) rowptr[NNODES] = NEDGES;
}

// P4: chunked scatter into bucket segments; runs are per-block contiguous (L2-local writes)
#define P4CHUNK 8192
__global__ void bscatter_kernel(const int* __restrict__ ei, const float* __restrict__ ew,
                                int* __restrict__ bcur, int2* __restrict__ tmp) {
  __shared__ int cnt[NBUCK];
  __shared__ int pos[NBUCK];
  int tid = threadIdx.x;
  for (int i = tid; i < NBUCK; i += 256) cnt[i] = 0;
  __syncthreads();
  int base = blockIdx.x * P4CHUNK;
  int end = base + P4CHUNK;
  if (end > NEDGES) end = NEDGES;
  for (int e = base + tid; e < end; e += 256)
    atomicAdd(&cnt[ei[NEDGES + e] >> BSH], 1);
  __syncthreads();
  for (int i = tid; i < NBUCK; i += 256)
    if (cnt[i]) pos[i] = atomicAdd(&bcur[i], cnt[i]);
  __syncthreads();
  for (int e = base + tid; e < end; e += 256) {
    int d = ei[NEDGES + e];
    int b = d >> BSH;
    int p = atomicAdd(&pos[b], 1);
    tmp[p] = make_int2(ei[e] | ((d & 127) << 17), __float_as_int(ew[e]));  // src<2^17
  }
}

// P5: one block per bucket — exact per-node sort within the 128-node window,
// writes rowptr + final edat (all writes in a single-owner 16KB window)
__global__ void bsort_kernel(const int* __restrict__ bbase, const int2* __restrict__ tmp,
                             int2* __restrict__ edat, int* __restrict__ rowptr) {
  __shared__ int hist[128];
  __shared__ int cur[128];
  int b = blockIdx.x;
  int tid = threadIdx.x;
  int base = bbase[b], cnt = bbase[b + 1] - base;
  if (tid < 128) hist[tid] = 0;
  __syncthreads();
  for (int i = tid; i < cnt; i += 256)
    atomicAdd(&hist[(tmp[base + i].x >> 17) & 127], 1);
  __syncthreads();
  int c = (tid < 128) ? hist[tid] : 0;
  if (tid < 128) cur[tid] = c;
  __syncthreads();
  for (int off = 1; off < 128; off <<= 1) {
    int v = (tid < 128 && tid >= off) ? cur[tid - off] : 0;
    __syncthreads();
    if (tid < 128) cur[tid] += v;
    __syncthreads();
  }
  if (tid < 128) {
    int ex = cur[tid] - c;
    int node = (b << BSH) + tid;
    if (node < NNODES) rowptr[node] = base + ex;
    cur[tid] = base + ex;
  }
  __syncthreads();
  for (int i = tid; i < cnt; i += 256) {
    int2 r = tmp[base + i];
    int d = (r.x >> 17) & 127;
    int p = atomicAdd(&cur[d], 1);
    edat[p] = make_int2(r.x & 0x1FFFF, r.y);
  }
}

// ---------------- tiled MFMA GEMM: 128x128 tile, BK=64, 4 waves of 64x64 ----------------
// grid = dim3(nyt, mblocks): N-tile varies fastest so blocks sharing an A-tile are
// dispatch-adjacent -> A fetched from HBM once, second read hits L2/L3.
#define LDSTR 72
template <bool AF32, int EPI>
__launch_bounds__(256, 2)
__global__ void gemm_tiled(const void* __restrict__ Aptr, int K,
                           const short* __restrict__ Wt,
                           void* __restrict__ Cp0, float* __restrict__ Cp1,
                           const float* __restrict__ bias, int nvalid, int ldc) {
  __shared__ __align__(16) short As[128 * LDSTR];
  __shared__ __align__(16) short Bs[128 * LDSTR];
  int tid = threadIdx.x;
  int lane = tid & 63, wv = tid >> 6;
  int wr = wv >> 1, wc = wv & 1;
  int m0 = blockIdx.y * 128;
  int n0 = blockIdx.x * 128;
  f32x4 acc[4][4];
#pragma unroll
  for (int i = 0; i < 4; i++)
#pragma unroll
    for (int j = 0; j < 4; j++) acc[i][j] = (f32x4){0.f, 0.f, 0.f, 0.f};

  int srow = tid >> 3;
  int scol = (tid & 7) * 8;

  for (int k0 = 0; k0 < K; k0 += 64) {
#pragma unroll
    for (int p = 0; p < 4; p++) {
      int ml = p * 32 + srow;
      int arow = m0 + ml;
      if (arow >= NNODES) arow = NNODES - 1;
      bf16x8 av;
      if (AF32) {
        const float* ap = (const float*)Aptr + (size_t)arow * K + k0 + scol;
        f32x4 a0 = *(const f32x4*)ap;
        f32x4 a1 = *(const f32x4*)(ap + 4);
#pragma unroll
        for (int j = 0; j < 4; j++) { av[j] = f2bf(a0[j]); av[4 + j] = f2bf(a1[j]); }
      } else {
        av = *(const bf16x8*)((const short*)Aptr + (size_t)arow * K + k0 + scol);
      }
      *(bf16x8*)&As[ml * LDSTR + scol] = av;
      bf16x8 bv = *(const bf16x8*)(Wt + (size_t)(n0 + ml) * K + k0 + scol);
      *(bf16x8*)&Bs[ml * LDSTR + scol] = bv;
    }
    __syncthreads();
    int r = lane & 15, quad = lane >> 4;
#pragma unroll
    for (int kk = 0; kk < 64; kk += 32) {
      bf16x8 af[4], bfr[4];
#pragma unroll
      for (int i = 0; i < 4; i++)
        af[i] = *(const bf16x8*)&As[(wr * 64 + i * 16 + r) * LDSTR + kk + quad * 8];
#pragma unroll
      for (int j = 0; j < 4; j++)
        bfr[j] = *(const bf16x8*)&Bs[(wc * 64 + j * 16 + r) * LDSTR + kk + quad * 8];
#pragma unroll
      for (int i = 0; i < 4; i++)
#pragma unroll
        for (int j = 0; j < 4; j++)
          acc[i][j] = __builtin_amdgcn_mfma_f32_16x16x32_bf16(af[i], bfr[j], acc[i][j], 0, 0, 0);
    }
    __syncthreads();
  }

  int quad = lane >> 4, cl = lane & 15;
#pragma unroll
  for (int i = 0; i < 4; i++) {
    int rowb = m0 + wr * 64 + i * 16 + quad * 4;
#pragma unroll
    for (int rr = 0; rr < 4; rr++) {
      int row = rowb + rr;
      if (row < NNODES) {
#pragma unroll
        for (int j = 0; j < 4; j++) {
          int col = n0 + wc * 64 + j * 16 + cl;
          float v = acc[i][j][rr];
          if (EPI == 0) {
            ((short*)Cp0)[(size_t)row * ldc + col] = f2bf(v);
          } else if (EPI == 1) {
            if (col < nvalid) Cp1[(size_t)row * nvalid + col] = v;
          } else {
            if (col < 128) ((short*)Cp0)[(size_t)row * 128 + col] = f2bf(v);
            else Cp1[(size_t)row * 128 + (col - 128)] = v + bias[col - 128];
          }
        }
      }
    }
  }
}

// ---------------- SpMM d=256 bf16, 8 gathers in flight ----------------
__global__ void spmm1_kernel(const int* __restrict__ rowptr, const int2* __restrict__ edat,
                             const short* __restrict__ S,
                             const float* __restrict__ bias, short* __restrict__ H) {
  int node = blockIdx.x * 4 + (threadIdx.x >> 6);
  if (node >= NNODES) return;
  int lane = threadIdx.x & 63;
  int c0 = lane * 4;
  const short* Sc = S + c0;
  f32x4 acc0 = (f32x4){0.f, 0.f, 0.f, 0.f};
  f32x4 acc1 = (f32x4){0.f, 0.f, 0.f, 0.f};
  int beg = rowptr[node], end = rowptr[node + 1];
  int i = beg;
  for (; i + 8 <= end; i += 8) {
    int2 e[8];
    bf16x4 v[8];
#pragma unroll
    for (int j = 0; j < 8; j++) e[j] = edat[i + j];
#pragma unroll
    for (int j = 0; j < 8; j++) v[j] = *(const bf16x4*)(Sc + (size_t)e[j].x * 256);
#pragma unroll
    for (int j = 0; j < 8; j++) {
      float w = __int_as_float(e[j].y);
      if (j & 1) fma4(acc1, w, v[j]); else fma4(acc0, w, v[j]);
    }
  }
  for (; i < end; i++) {
    int2 e = edat[i];
    fma4(acc0, __int_as_float(e.y), *(const bf16x4*)(Sc + (size_t)e.x * 256));
  }
  f32x4 a;
  a[0] = acc0[0] + acc1[0]; a[1] = acc0[1] + acc1[1];
  a[2] = acc0[2] + acc1[2]; a[3] = acc0[3] + acc1[3];
  f32x4 b = *(const f32x4*)(bias + c0);
  bf16x4 h;
#pragma unroll
  for (int j = 0; j < 4; j++) h[j] = f2bf(fmaxf(a[j] + b[j], 0.f));
  *(bf16x4*)(H + (size_t)node * 256 + c0) = h;
}

// ---------------- SpMM d=128 bf16, 8 gathers in flight ----------------
__global__ void spmm2_kernel(const int* __restrict__ rowptr, const int2* __restrict__ edat,
                             const short* __restrict__ S,
                             const float* __restrict__ bias, short* __restrict__ H) {
  int node = blockIdx.x * 4 + (threadIdx.x >> 6);
  if (node >= NNODES) return;
  int lane = threadIdx.x & 63;
  int c0 = lane * 2;
  const short* Sc = S + c0;
  f32x2 acc0 = (f32x2){0.f, 0.f};
  f32x2 acc1 = (f32x2){0.f, 0.f};
  int beg = rowptr[node], end = rowptr[node + 1];
  int i = beg;
  for (; i + 8 <= end; i += 8) {
    int2 e[8];
    bf16x2 v[8];
#pragma unroll
    for (int j = 0; j < 8; j++) e[j] = edat[i + j];
#pragma unroll
    for (int j = 0; j < 8; j++) v[j] = *(const bf16x2*)(Sc + (size_t)e[j].x * 128);
#pragma unroll
    for (int j = 0; j < 8; j++) {
      float w = __int_as_float(e[j].y);
      if (j & 1) fma2(acc1, w, v[j]); else fma2(acc0, w, v[j]);
    }
  }
  for (; i < end; i++) {
    int2 e = edat[i];
    fma2(acc0, __int_as_float(e.y), *(const bf16x2*)(Sc + (size_t)e.x * 128));
  }
  float a0 = acc0[0] + acc1[0], a1 = acc0[1] + acc1[1];
  bf16x2 h;
  h[0] = f2bf(fmaxf(a0 + bias[c0 + 0], 0.f));
  h[1] = f2bf(fmaxf(a1 + bias[c0 + 1], 0.f));
  *(bf16x2*)(H + (size_t)node * 128 + c0) = h;
}

// ---------------- SpMM d=40 f32 + bias + log_softmax, 8 gathers in flight ----------------
__global__ void spmm3_kernel(const int* __restrict__ rowptr, const int2* __restrict__ edat,
                             const float* __restrict__ S3,
                             const float* __restrict__ b3, float* __restrict__ out1) {
  int node = blockIdx.x * 4 + (threadIdx.x >> 6);
  if (node >= NNODES) return;
  int lane = threadIdx.x & 63;
  bool act = lane < 40;
  float acc0 = 0.f, acc1 = 0.f;
  int beg = rowptr[node], end = rowptr[node + 1];
  if (act) {
    int i = beg;
    for (; i + 8 <= end; i += 8) {
      int2 e[8];
      float v[8];
#pragma unroll
      for (int j = 0; j < 8; j++) e[j] = edat[i + j];
#pragma unroll
      for (int j = 0; j < 8; j++) v[j] = S3[(size_t)e[j].x * 40 + lane];
#pragma unroll
      for (int j = 0; j < 8; j++) {
        float w = __int_as_float(e[j].y);
        if (j & 1) acc1 = fmaf(w, v[j], acc1); else acc0 = fmaf(w, v[j], acc0);
      }
    }
    for (; i < end; i++) {
      int2 e = edat[i];
      acc0 = fmaf(__int_as_float(e.y), S3[(size_t)e.x * 40 + lane], acc0);
    }
  }
  float acc = acc0 + acc1;
  if (act) acc += b3[lane];
  float v = act ? acc : -__builtin_inff();
  for (int off = 32; off > 0; off >>= 1) v = fmaxf(v, __shfl_xor(v, off));
  float e = act ? expf(acc - v) : 0.f;
  for (int off = 32; off > 0; off >>= 1) e += __shfl_xor(e, off);
  float ls = logf(e);
  if (act) out1[(size_t)node * 40 + lane] = acc - v - ls;
}

extern "C" void kernel_launch(void* const* d_in, const int* in_sizes, int n_in,
                              void* d_out, int out_size, void* d_ws, size_t ws_size,
                              hipStream_t stream) {
  const float* x  = (const float*)d_in[0];
  const int*   ei = (const int*)d_in[1];
  const float* ew = (const float*)d_in[2];
  const float* W1 = (const float*)d_in[3];
  const float* b1 = (const float*)d_in[4];
  const float* W2 = (const float*)d_in[5];
  const float* b2 = (const float*)d_in[6];
  const float* W3 = (const float*)d_in[7];
  const float* b3 = (const float*)d_in[8];
  const float* We = (const float*)d_in[9];
  const float* be = (const float*)d_in[10];
  float* out1 = (float*)d_out;
  float* out2 = (float*)d_out + (size_t)NNODES * 40;

  char* w = (char*)d_ws;
  size_t off = 0;
  auto alloc = [&](size_t bytes) -> char* {
    char* p = w + off;
    off += (bytes + 255) & ~(size_t)255;
    return p;
  };
  int*   rowptr = (int*)alloc((size_t)(NNODES + 1) * 4);
  int*   bcnt   = (int*)alloc((size_t)NBUCK * 4);
  int*   bbase  = (int*)alloc((size_t)(NBUCK + 1) * 4);
  int*   bcur   = (int*)alloc((size_t)NBUCK * 4);
  int2*  edat   = (int2*)alloc((size_t)NEDGES * 8);
  short* Wt1    = (short*)alloc((size_t)256 * 512 * 2);
  short* Wt2e   = (short*)alloc((size_t)256 * 256 * 2);
  short* Wt3    = (short*)alloc((size_t)128 * 128 * 2);
  short* S1bf   = (short*)alloc((size_t)NNODES * 256 * 2);
  short* Hbf    = (short*)alloc((size_t)NNODES * 256 * 2);
  short* S2bf   = (short*)alloc((size_t)NNODES * 128 * 2);
  short* Tbf    = (short*)alloc((size_t)NNODES * 128 * 2);
  float* S3     = (float*)alloc((size_t)NNODES * 40 * 4);  // 16 MB
  int2*  tmp    = (int2*)S3;  // alias: tmp (12.8 MB) dead before gemm3 writes S3

  // --- CSR build: two-level counting sort ---
  hipMemsetAsync(bcnt, 0, (size_t)NBUCK * 4, stream);
  bcount_kernel<<<256, 256, 0, stream>>>(ei, bcnt);
  bscan_kernel<<<1, 1024, 0, stream>>>(bcnt, bbase, bcur, rowptr);
  bscatter_kernel<<<(NEDGES + P4CHUNK - 1) / P4CHUNK, 256, 0, stream>>>(ei, ew, bcur, tmp);
  bsort_kernel<<<NBUCK, 256, 0, stream>>>(bbase, tmp, edat, rowptr);

  // --- weight transpose+bf16 ---
  wtrans_kernel<<<(256 * 512 + 255) / 256, 256, 0, stream>>>(W1, Wt1, 512, 256, 256);
  wtrans_kernel<<<(128 * 256 + 255) / 256, 256, 0, stream>>>(W2, Wt2e, 256, 128, 128);
  wtrans_kernel<<<(128 * 256 + 255) / 256, 256, 0, stream>>>(We, Wt2e + (size_t)128 * 256, 256, 128, 128);
  wtrans_kernel<<<(128 * 128 + 255) / 256, 256, 0, stream>>>(W3, Wt3, 128, 40, 128);

  int gblocks = (NNODES + 127) / 128;
  int sblocks = (NNODES + 3) / 4;

  gemm_tiled<true, 0><<<dim3(2, gblocks), 256, 0, stream>>>(x, 512, Wt1, S1bf, nullptr, nullptr, 256, 256);
  spmm1_kernel<<<sblocks, 256, 0, stream>>>(rowptr, edat, S1bf, b1, Hbf);
  gemm_tiled<false, 2><<<dim3(2, gblocks), 256, 0, stream>>>(Hbf, 256, Wt2e, S2bf, out2, be, 256, 128);
  spmm2_kernel<<<sblocks, 256, 0, stream>>>(rowptr, edat, S2bf, b2, Tbf);
  gemm_tiled<false, 1><<<dim3(1, gblocks), 256, 0, stream>>>(Tbf, 128, Wt3, nullptr, S3, nullptr, 40, 40);
  spmm3_kernel<<<sblocks, 256, 0, stream>>>(rowptr, edat, S3, b3, out1);
}